// Round 13
// baseline (2386.211 us; speedup 1.0000x reference)
//
#include <hip/hip_runtime.h>
#include <math.h>

#define NPTS 16384
#define KNN 32
#define NB 8
#define CD 83
#define CDP 84      // padded row: 336 B, 16B-aligned
#define PDIM 35
#define QPB 32      // queries per knn block
#define NSL 4       // candidate slices per query
#define TS 64       // candidate tile rows

__device__ __forceinline__ int bval(const int* __restrict__ p, int i, int is32) {
    return is32 ? p[i] : p[2 * i];
}

// ===== numpy universal-intrinsics f32 sin/cos (loops_trigonometric.dispatch) =====
__device__ __forceinline__ float np_sincos_f32(float x, int compute_cos) {
    const float two_over_pi = 0x1.45f306p-1f;
    const float c1 = -0x1.921fb0p+00f;
    const float c2 = -0x1.5110b4p-22f;
    const float c3 = -0x1.846988p-48f;
    const float rint_cvt = 12582912.0f;
    float q = __fsub_rn(__fadd_rn(__fmul_rn(x, two_over_pi), rint_cvt), rint_cvt);
    float rx = __builtin_fmaf(q, c1, x);
    rx = __builtin_fmaf(q, c2, rx);
    rx = __builtin_fmaf(q, c3, rx);
    float r2 = __fmul_rn(rx, rx);
    float yc = __builtin_fmaf(0x1.98e616p-16f, r2, -0x1.6c06dcp-10f);
    yc = __builtin_fmaf(yc, r2, 0x1.55553cp-05f);
    yc = __builtin_fmaf(yc, r2, -0x1.000000p-1f);
    yc = __builtin_fmaf(yc, r2, 0x1.000000p+0f);
    float ys = __builtin_fmaf(0x1.7d3bbcp-19f, r2, -0x1.a06bbap-13f);
    ys = __builtin_fmaf(ys, r2, 0x1.11119ap-07f);
    ys = __builtin_fmaf(ys, r2, -0x1.555556p-03f);
    ys = __fmul_rn(ys, r2);
    ys = __builtin_fmaf(ys, rx, rx);
    int iq = (int)q + compute_cos;
    float res = ((iq & 1) == 0) ? ys : yc;
    if (iq & 2) res = __int_as_float(__float_as_int(res) ^ 0x80000000u);
    return res;
}

// ===== numpy FLOAT_exp (loops_exponent_log.dispatch — Cephes expf, FMA form) =====
__device__ __forceinline__ float np_exp_f32(float x) {
    const float log2e = 1.442695040f;
    const float rint_cvt = 12582912.0f;
    if (x < -87.33654f) return 0.0f;
    float q = __fsub_rn(__fadd_rn(__fmul_rn(x, log2e), rint_cvt), rint_cvt);
    float r = __builtin_fmaf(q, -0.693359375f, x);
    r = __builtin_fmaf(q, 2.12194440e-4f, r);
    float y = 1.9875691500e-4f;
    y = __builtin_fmaf(y, r, 1.3981999507e-3f);
    y = __builtin_fmaf(y, r, 8.3334519073e-3f);
    y = __builtin_fmaf(y, r, 4.1665795894e-2f);
    y = __builtin_fmaf(y, r, 1.6666665459e-1f);
    y = __builtin_fmaf(y, r, 5.0000001201e-1f);
    float r2 = __fmul_rn(r, r);
    y = __builtin_fmaf(y, r2, r);
    y = __fadd_rn(y, 1.0f);
    int iq = (int)q;
    float sc = __int_as_float((127 + iq) << 23);
    return __fmul_rn(y, sc);
}

// ===== OpenBLAS sgemv_t 8-lane order =====
__device__ __forceinline__ float np_gemv32(const float* h, const float* __restrict__ w) {
    float a0 = 0.f, a1 = 0.f, a2 = 0.f, a3 = 0.f, a4 = 0.f, a5 = 0.f, a6 = 0.f, a7 = 0.f;
    #pragma unroll
    for (int t = 0; t < 32; t += 8) {
        a0 = __builtin_fmaf(h[t],     w[t],     a0);
        a1 = __builtin_fmaf(h[t + 1], w[t + 1], a1);
        a2 = __builtin_fmaf(h[t + 2], w[t + 2], a2);
        a3 = __builtin_fmaf(h[t + 3], w[t + 3], a3);
        a4 = __builtin_fmaf(h[t + 4], w[t + 4], a4);
        a5 = __builtin_fmaf(h[t + 5], w[t + 5], a5);
        a6 = __builtin_fmaf(h[t + 6], w[t + 6], a6);
        a7 = __builtin_fmaf(h[t + 7], w[t + 7], a7);
    }
    float s0 = __fadd_rn(a0, a4);
    float s1 = __fadd_rn(a1, a5);
    float s2 = __fadd_rn(a2, a6);
    float s3 = __fadd_rn(a3, a7);
    return __fadd_rn(__fadd_rn(s0, s1), __fadd_rn(s2, s3));
}

__global__ void k_flag(const int* __restrict__ batch32, int* __restrict__ flag) {
    if (threadIdx.x == 0) flag[0] = (batch32[NPTS - 1] != 0) ? 1 : 0;
}

__global__ void k_bounds(const int* __restrict__ batch, const int* __restrict__ flag,
                         int* __restrict__ seg) {
    int b = threadIdx.x;
    if (b > NB) return;
    int is32 = flag[0];
    int lo = 0, hi = NPTS;
    while (lo < hi) { int mid = (lo + hi) >> 1; if (bval(batch, mid, is32) < b) lo = mid + 1; else hi = mid; }
    seg[b] = lo;
}

// ---- front-end: identical arithmetic to R12; weights staged in LDS; 84-stride output ----
__global__ void __launch_bounds__(256) k_front(
    const float* __restrict__ x, const float* __restrict__ pos,
    const float* __restrict__ w1f, const float* __restrict__ b1f,
    const float* __restrict__ w2f, const float* __restrict__ b2f,
    const float* __restrict__ w1p, const float* __restrict__ b1p,
    const float* __restrict__ w2p, const float* __restrict__ b2p,
    float* __restrict__ comb)
{
    __shared__ float s_w1f[48 * 32];
    __shared__ float s_w1p[35 * 32];
    __shared__ float s_b1f[32], s_w2f[32], s_b1p[32], s_w2p[32];
    __shared__ float s_b2[2];
    int t = threadIdx.x;
    for (int idx = t; idx < 48 * 32; idx += 256) s_w1f[idx] = w1f[idx];
    for (int idx = t; idx < 35 * 32; idx += 256) s_w1p[idx] = w1p[idx];
    if (t < 32) { s_b1f[t] = b1f[t]; s_w2f[t] = w2f[t]; s_b1p[t] = b1p[t]; s_w2p[t] = w2p[t]; }
    if (t == 0) { s_b2[0] = b2f[0]; s_b2[1] = b2p[0]; }
    __syncthreads();

    int i = blockIdx.x * 256 + t;

    // x row via float4 (values identical)
    float xr[16];
    const float4* x4 = (const float4*)(x + (long)i * 16);
    #pragma unroll
    for (int d4 = 0; d4 < 4; ++d4) {
        float4 v = x4[d4];
        xr[4 * d4] = v.x; xr[4 * d4 + 1] = v.y; xr[4 * d4 + 2] = v.z; xr[4 * d4 + 3] = v.w;
    }
    float p0 = pos[i * 3], p1 = pos[i * 3 + 1], p2 = pos[i * 3 + 2];

    float enc[32];
    #pragma unroll
    for (int f = 0; f < 16; ++f) {
        float fbf = (float)((double)f * (9.0 / 63.0) + 1.0);
        float a = __fmul_rn(p0, fbf);
        enc[2 * f] = np_sincos_f32(a, 0);
        enc[2 * f + 1] = np_sincos_f32(a, 1);
    }

    float h[32], hr[32];
    #pragma unroll
    for (int j = 0; j < 32; ++j) h[j] = 0.0f;
    #pragma unroll
    for (int k = 0; k < 16; ++k) {
        float v = xr[k];
        #pragma unroll
        for (int j = 0; j < 32; ++j) h[j] = __builtin_fmaf(v, s_w1f[k * 32 + j], h[j]);
    }
    for (int e = 0; e < 32; ++e) {
        float v = enc[e];
        #pragma unroll
        for (int j = 0; j < 32; ++j) h[j] = __builtin_fmaf(v, s_w1f[(16 + e) * 32 + j], h[j]);
    }
    #pragma unroll
    for (int j = 0; j < 32; ++j) hr[j] = fmaxf(__fadd_rn(h[j], s_b1f[j]), 0.0f);
    float fw = __fadd_rn(np_gemv32(hr, s_w2f), s_b2[0]);

    #pragma unroll
    for (int j = 0; j < 32; ++j) h[j] = 0.0f;
    {
        #pragma unroll
        for (int j = 0; j < 32; ++j) h[j] = __builtin_fmaf(p0, s_w1p[0 * 32 + j], h[j]);
        #pragma unroll
        for (int j = 0; j < 32; ++j) h[j] = __builtin_fmaf(p1, s_w1p[1 * 32 + j], h[j]);
        #pragma unroll
        for (int j = 0; j < 32; ++j) h[j] = __builtin_fmaf(p2, s_w1p[2 * 32 + j], h[j]);
    }
    for (int e = 0; e < 32; ++e) {
        float v = enc[e];
        #pragma unroll
        for (int j = 0; j < 32; ++j) h[j] = __builtin_fmaf(v, s_w1p[(3 + e) * 32 + j], h[j]);
    }
    #pragma unroll
    for (int j = 0; j < 32; ++j) hr[j] = fmaxf(__fadd_rn(h[j], s_b1p[j]), 0.0f);
    float pw = __fadd_rn(np_gemv32(hr, s_w2p), s_b2[1]);

    float m = fmaxf(fw, pw);
    float e0 = np_exp_f32(__fsub_rn(fw, m));
    float e1 = np_exp_f32(__fsub_rn(pw, m));
    float s = __fadd_rn(e0, e1);
    float sw0 = __fdiv_rn(e0, s);   // scales feat
    float sw1 = __fdiv_rn(e1, s);   // scales pe

    float* out = comb + (long)i * CDP;
    out[0] = __fmul_rn(p0, sw1);
    out[1] = __fmul_rn(p1, sw1);
    out[2] = __fmul_rn(p2, sw1);
    #pragma unroll
    for (int e = 0; e < 32; ++e) out[3 + e] = __fmul_rn(enc[e], sw1);
    #pragma unroll
    for (int k = 0; k < 16; ++k) out[35 + k] = __fmul_rn(xr[k], sw0);
    #pragma unroll
    for (int e = 0; e < 32; ++e) out[51 + e] = __fmul_rn(enc[e], sw0);
    out[83] = 0.0f;   // pad (kept zero through k_z; makes fmaf(0,0,acc)=acc in knn)
}

// ---- segment stats: identical accumulation order; 8-deep load prefetch ----
__global__ void __launch_bounds__(128) k_stats(
    const float* __restrict__ comb, const int* __restrict__ seg,
    float* __restrict__ meanb, float* __restrict__ denb)
{
    int b = blockIdx.x;
    int d = threadIdx.x;
    if (d >= CD) return;
    int start = seg[b], end = seg[b + 1];
    float sum = 0.0f, ss = 0.0f;
    int r = start;
    for (; r + 8 <= end; r += 8) {
        float v0 = comb[(long)(r + 0) * CDP + d];
        float v1 = comb[(long)(r + 1) * CDP + d];
        float v2 = comb[(long)(r + 2) * CDP + d];
        float v3 = comb[(long)(r + 3) * CDP + d];
        float v4 = comb[(long)(r + 4) * CDP + d];
        float v5 = comb[(long)(r + 5) * CDP + d];
        float v6 = comb[(long)(r + 6) * CDP + d];
        float v7 = comb[(long)(r + 7) * CDP + d];
        sum = __fadd_rn(sum, v0); ss = __fadd_rn(ss, __fmul_rn(v0, v0));
        sum = __fadd_rn(sum, v1); ss = __fadd_rn(ss, __fmul_rn(v1, v1));
        sum = __fadd_rn(sum, v2); ss = __fadd_rn(ss, __fmul_rn(v2, v2));
        sum = __fadd_rn(sum, v3); ss = __fadd_rn(ss, __fmul_rn(v3, v3));
        sum = __fadd_rn(sum, v4); ss = __fadd_rn(ss, __fmul_rn(v4, v4));
        sum = __fadd_rn(sum, v5); ss = __fadd_rn(ss, __fmul_rn(v5, v5));
        sum = __fadd_rn(sum, v6); ss = __fadd_rn(ss, __fmul_rn(v6, v6));
        sum = __fadd_rn(sum, v7); ss = __fadd_rn(ss, __fmul_rn(v7, v7));
    }
    for (; r < end; ++r) {
        float c = comb[(long)r * CDP + d];
        sum = __fadd_rn(sum, c);
        ss = __fadd_rn(ss, __fmul_rn(c, c));
    }
    float cnt = (float)(end - start);
    float mn = __fdiv_rn(sum, fmaxf(cnt, 1.0f));
    float num = __fsub_rn(ss, __fmul_rn(__fmul_rn(cnt, mn), mn));
    float var = __fdiv_rn(num, fmaxf(__fsub_rn(cnt, 1.0f), 1.0f));
    if (var < 0.0f) var = 0.0f;
    meanb[b * CD + d] = mn;
    denb[b * CD + d] = __fadd_rn(__fsqrt_rn(var), 1e-8f);
}

// ---- z in place (float4 I/O); sq via np pairwise 8-acc tree — arithmetic identical ----
__global__ void __launch_bounds__(256) k_z(
    float* __restrict__ comb, const int* __restrict__ batch, const int* __restrict__ flag,
    const float* __restrict__ meanb, const float* __restrict__ denb,
    float* __restrict__ sqb)
{
    int r = blockIdx.x * 256 + threadIdx.x;
    int b = bval(batch, r, flag[0]);
    const float* mb = meanb + b * CD;
    const float* db = denb + b * CD;
    float4* row4 = (float4*)(comb + (long)r * CDP);
    float rv[CDP];
    #pragma unroll
    for (int d4 = 0; d4 < 21; ++d4) {
        float4 v = row4[d4];
        rv[4 * d4] = v.x; rv[4 * d4 + 1] = v.y; rv[4 * d4 + 2] = v.z; rv[4 * d4 + 3] = v.w;
    }
    float p[CD];
    for (int d = 0; d < CD; ++d) {
        float zz = __fdiv_rn(__fsub_rn(rv[d], mb[d]), db[d]);
        rv[d] = zz;
        p[d] = __fmul_rn(zz, zz);
    }
    rv[83] = 0.0f;
    #pragma unroll
    for (int d4 = 0; d4 < 21; ++d4) {
        float4 v;
        v.x = rv[4 * d4]; v.y = rv[4 * d4 + 1]; v.z = rv[4 * d4 + 2]; v.w = rv[4 * d4 + 3];
        row4[d4] = v;
    }
    float r0 = p[0], r1 = p[1], r2 = p[2], r3 = p[3];
    float r4 = p[4], r5 = p[5], r6 = p[6], r7 = p[7];
    #pragma unroll
    for (int i = 8; i < 80; i += 8) {
        r0 = __fadd_rn(r0, p[i]);     r1 = __fadd_rn(r1, p[i + 1]);
        r2 = __fadd_rn(r2, p[i + 2]); r3 = __fadd_rn(r3, p[i + 3]);
        r4 = __fadd_rn(r4, p[i + 4]); r5 = __fadd_rn(r5, p[i + 5]);
        r6 = __fadd_rn(r6, p[i + 6]); r7 = __fadd_rn(r7, p[i + 7]);
    }
    float res = __fadd_rn(__fadd_rn(__fadd_rn(r0, r1), __fadd_rn(r2, r3)),
                          __fadd_rn(__fadd_rn(r4, r5), __fadd_rn(r6, r7)));
    res = __fadd_rn(res, p[80]);
    res = __fadd_rn(res, p[81]);
    res = __fadd_rn(res, p[82]);
    sqb[r] = res;
}

// ---- KNN: 32 queries/block x 4 slices, LDS candidate tiles; dot chain bit-identical;
//      slice partition + (dist,idx)-lex merge == R12's stable ascending scan ----
__global__ void __launch_bounds__(128) k_knn(
    const float* __restrict__ z, const float* __restrict__ sqb,
    const int* __restrict__ batch, const int* __restrict__ flag,
    const int* __restrict__ seg, int* __restrict__ out)
{
    __shared__ union {
        struct { float zt[TS * CDP]; float sqt[TS]; } a;   // 21504 + 256 B
        struct { float kd[128 * KNN]; int ki[128 * KNN]; } m;  // 32768 B
    } sm;

    int t = threadIdx.x;
    int q = t >> 2, s = t & 3;
    int row0 = blockIdx.x * QPB;
    int i = row0 + q;
    int is32 = flag[0];
    int bi = bval(batch, i, is32);
    int my_lo = seg[bi], my_hi = seg[bi + 1];
    int b0 = bval(batch, row0, is32), b1 = bval(batch, row0 + QPB - 1, is32);
    int lo_blk = seg[b0], hi_blk = seg[b1 + 1];

    float zq[CDP];
    const float4* z4 = (const float4*)(z + (long)i * CDP);
    #pragma unroll
    for (int d4 = 0; d4 < 21; ++d4) {
        float4 v = z4[d4];
        zq[4 * d4] = v.x; zq[4 * d4 + 1] = v.y; zq[4 * d4 + 2] = v.z; zq[4 * d4 + 3] = v.w;
    }
    float sqi = sqb[i];

    float kd[KNN]; int ki[KNN];
    #pragma unroll
    for (int k = 0; k < KNN; ++k) { kd[k] = INFINITY; ki[k] = 0x7fffffff; }

    for (int tbase = lo_blk; tbase < hi_blk; tbase += TS) {
        int cnt = min(TS, hi_blk - tbase);
        __syncthreads();
        {   // stage tile: contiguous float4 copy (rows are 336B, 16B-aligned)
            const float4* src = (const float4*)(z + (long)tbase * CDP);
            float4* dst = (float4*)sm.a.zt;
            for (int idx = t; idx < cnt * 21; idx += 128) dst[idx] = src[idx];
            for (int rr = t; rr < cnt; rr += 128) sm.a.sqt[rr] = sqb[tbase + rr];
        }
        __syncthreads();

        for (int jj = s; jj < cnt; jj += NSL) {
            int jg = tbase + jj;
            if (jg < my_lo || jg >= my_hi) continue;
            const float* zr = &sm.a.zt[jj * CDP];
            float acc = 0.0f;
            #pragma unroll
            for (int d = 0; d < CDP; ++d) acc = __builtin_fmaf(zq[d], zr[d], acc); // d=83: fmaf(0,0,acc)=acc
            float dist = __fsub_rn(__fadd_rn(sqi, sm.a.sqt[jj]), __fmul_rn(2.0f, acc));
            if (dist < kd[KNN - 1] || (dist == kd[KNN - 1] && jg < ki[KNN - 1])) {
                kd[KNN - 1] = dist; ki[KNN - 1] = jg;
                #pragma unroll
                for (int k = KNN - 2; k >= 0; --k) {
                    bool sw = (kd[k + 1] < kd[k]) || (kd[k + 1] == kd[k] && ki[k + 1] < ki[k]);
                    if (sw) {
                        float td = kd[k]; kd[k] = kd[k + 1]; kd[k + 1] = td;
                        int ti = ki[k]; ki[k] = ki[k + 1]; ki[k + 1] = ti;
                    }
                }
            }
        }
    }

    __syncthreads();
    #pragma unroll
    for (int k = 0; k < KNN; ++k) { sm.m.kd[t * KNN + k] = kd[k]; sm.m.ki[t * KNN + k] = ki[k]; }
    __syncthreads();

    if (s == 0) {
        const float* Ld = &sm.m.kd[t * KNN];   // 4 slice rows: t, t+1, t+2, t+3
        const int* Li = &sm.m.ki[t * KNN];
        int p0 = 0, p1 = 0, p2 = 0, p3 = 0;
        int* orow = out;
        int* ocol = out + (long)NPTS * KNN;
        for (int k = 0; k < KNN; ++k) {
            float d0 = (p0 < KNN) ? Ld[p0] : INFINITY;           int i0 = (p0 < KNN) ? Li[p0] : 0x7fffffff;
            float d1 = (p1 < KNN) ? Ld[KNN + p1] : INFINITY;     int i1 = (p1 < KNN) ? Li[KNN + p1] : 0x7fffffff;
            float d2 = (p2 < KNN) ? Ld[2 * KNN + p2] : INFINITY; int i2 = (p2 < KNN) ? Li[2 * KNN + p2] : 0x7fffffff;
            float d3 = (p3 < KNN) ? Ld[3 * KNN + p3] : INFINITY; int i3 = (p3 < KNN) ? Li[3 * KNN + p3] : 0x7fffffff;
            float bd = d0; int bix = i0; int bl = 0;
            if (d1 < bd || (d1 == bd && i1 < bix)) { bd = d1; bix = i1; bl = 1; }
            if (d2 < bd || (d2 == bd && i2 < bix)) { bd = d2; bix = i2; bl = 2; }
            if (d3 < bd || (d3 == bd && i3 < bix)) { bd = d3; bix = i3; bl = 3; }
            if (bl == 0) p0++; else if (bl == 1) p1++; else if (bl == 2) p2++; else p3++;
            orow[(long)i * KNN + k] = i;
            ocol[(long)i * KNN + k] = bix;
        }
    }
}

extern "C" void kernel_launch(void* const* d_in, const int* in_sizes, int n_in,
                              void* d_out, int out_size, void* d_ws, size_t ws_size,
                              hipStream_t stream)
{
    const float* x   = (const float*)d_in[0];
    const float* pos = (const float*)d_in[1];
    const int* batch = (const int*)d_in[2];
    const float* w1f = (const float*)d_in[3];
    const float* b1f = (const float*)d_in[4];
    const float* w2f = (const float*)d_in[5];
    const float* b2f = (const float*)d_in[6];
    const float* w1p = (const float*)d_in[7];
    const float* b1p = (const float*)d_in[8];
    const float* w2p = (const float*)d_in[9];
    const float* b2p = (const float*)d_in[10];

    char* ws = (char*)d_ws;
    float* comb  = (float*)(ws);                // N*84*4 = 5,505,024 (combined, then z in place)
    float* sqb   = (float*)(ws + 5505024);      // N*4    = 65,536
    float* meanb = (float*)(ws + 5570560);      // 664*4  = 2,656
    float* denb  = (float*)(ws + 5573216);      // 664*4  = 2,656
    int*   seg   = (int*)  (ws + 5575936);      // 9 ints
    int*   flag  = (int*)  (ws + 5576000);      // 1 int
    int* out = (int*)d_out;

    hipLaunchKernelGGL(k_flag, dim3(1), dim3(64), 0, stream, batch, flag);
    hipLaunchKernelGGL(k_bounds, dim3(1), dim3(16), 0, stream, batch, flag, seg);
    hipLaunchKernelGGL(k_front, dim3(NPTS / 256), dim3(256), 0, stream,
                       x, pos, w1f, b1f, w2f, b2f, w1p, b1p, w2p, b2p, comb);
    hipLaunchKernelGGL(k_stats, dim3(NB), dim3(128), 0, stream, comb, seg, meanb, denb);
    hipLaunchKernelGGL(k_z, dim3(NPTS / 256), dim3(256), 0, stream, comb, batch, flag, meanb, denb, sqb);
    hipLaunchKernelGGL(k_knn, dim3(NPTS / QPB), dim3(128), 0, stream, comb, sqb, batch, flag, seg, out);
}

// Round 14
// 884.704 us; speedup vs baseline: 2.6972x; 2.6972x over previous
//
#include <hip/hip_runtime.h>
#include <math.h>

#define NPTS 16384
#define KNN 32
#define NB 8
#define CD 83
#define CDP 84      // padded row: 336 B, 16B-aligned
#define PDIM 35
#define QPB 16      // queries per knn block
#define NSL 8       // candidate slices per query
#define MST 33      // merge-list LDS stride (pad vs 32 to avoid bank conflicts)

__device__ __forceinline__ int bval(const int* __restrict__ p, int i, int is32) {
    return is32 ? p[i] : p[2 * i];
}

// ===== numpy universal-intrinsics f32 sin/cos (loops_trigonometric.dispatch) =====
__device__ __forceinline__ float np_sincos_f32(float x, int compute_cos) {
    const float two_over_pi = 0x1.45f306p-1f;
    const float c1 = -0x1.921fb0p+00f;
    const float c2 = -0x1.5110b4p-22f;
    const float c3 = -0x1.846988p-48f;
    const float rint_cvt = 12582912.0f;
    float q = __fsub_rn(__fadd_rn(__fmul_rn(x, two_over_pi), rint_cvt), rint_cvt);
    float rx = __builtin_fmaf(q, c1, x);
    rx = __builtin_fmaf(q, c2, rx);
    rx = __builtin_fmaf(q, c3, rx);
    float r2 = __fmul_rn(rx, rx);
    float yc = __builtin_fmaf(0x1.98e616p-16f, r2, -0x1.6c06dcp-10f);
    yc = __builtin_fmaf(yc, r2, 0x1.55553cp-05f);
    yc = __builtin_fmaf(yc, r2, -0x1.000000p-1f);
    yc = __builtin_fmaf(yc, r2, 0x1.000000p+0f);
    float ys = __builtin_fmaf(0x1.7d3bbcp-19f, r2, -0x1.a06bbap-13f);
    ys = __builtin_fmaf(ys, r2, 0x1.11119ap-07f);
    ys = __builtin_fmaf(ys, r2, -0x1.555556p-03f);
    ys = __fmul_rn(ys, r2);
    ys = __builtin_fmaf(ys, rx, rx);
    int iq = (int)q + compute_cos;
    float res = ((iq & 1) == 0) ? ys : yc;
    if (iq & 2) res = __int_as_float(__float_as_int(res) ^ 0x80000000u);
    return res;
}

// ===== numpy FLOAT_exp (loops_exponent_log.dispatch — Cephes expf, FMA form) =====
__device__ __forceinline__ float np_exp_f32(float x) {
    const float log2e = 1.442695040f;
    const float rint_cvt = 12582912.0f;
    if (x < -87.33654f) return 0.0f;
    float q = __fsub_rn(__fadd_rn(__fmul_rn(x, log2e), rint_cvt), rint_cvt);
    float r = __builtin_fmaf(q, -0.693359375f, x);
    r = __builtin_fmaf(q, 2.12194440e-4f, r);
    float y = 1.9875691500e-4f;
    y = __builtin_fmaf(y, r, 1.3981999507e-3f);
    y = __builtin_fmaf(y, r, 8.3334519073e-3f);
    y = __builtin_fmaf(y, r, 4.1665795894e-2f);
    y = __builtin_fmaf(y, r, 1.6666665459e-1f);
    y = __builtin_fmaf(y, r, 5.0000001201e-1f);
    float r2 = __fmul_rn(r, r);
    y = __builtin_fmaf(y, r2, r);
    y = __fadd_rn(y, 1.0f);
    int iq = (int)q;
    float sc = __int_as_float((127 + iq) << 23);
    return __fmul_rn(y, sc);
}

// ===== OpenBLAS sgemv_t 8-lane order =====
__device__ __forceinline__ float np_gemv32(const float* h, const float* __restrict__ w) {
    float a0 = 0.f, a1 = 0.f, a2 = 0.f, a3 = 0.f, a4 = 0.f, a5 = 0.f, a6 = 0.f, a7 = 0.f;
    #pragma unroll
    for (int t = 0; t < 32; t += 8) {
        a0 = __builtin_fmaf(h[t],     w[t],     a0);
        a1 = __builtin_fmaf(h[t + 1], w[t + 1], a1);
        a2 = __builtin_fmaf(h[t + 2], w[t + 2], a2);
        a3 = __builtin_fmaf(h[t + 3], w[t + 3], a3);
        a4 = __builtin_fmaf(h[t + 4], w[t + 4], a4);
        a5 = __builtin_fmaf(h[t + 5], w[t + 5], a5);
        a6 = __builtin_fmaf(h[t + 6], w[t + 6], a6);
        a7 = __builtin_fmaf(h[t + 7], w[t + 7], a7);
    }
    float s0 = __fadd_rn(a0, a4);
    float s1 = __fadd_rn(a1, a5);
    float s2 = __fadd_rn(a2, a6);
    float s3 = __fadd_rn(a3, a7);
    return __fadd_rn(__fadd_rn(s0, s1), __fadd_rn(s2, s3));
}

__global__ void k_flag(const int* __restrict__ batch32, int* __restrict__ flag) {
    if (threadIdx.x == 0) flag[0] = (batch32[NPTS - 1] != 0) ? 1 : 0;
}

__global__ void k_bounds(const int* __restrict__ batch, const int* __restrict__ flag,
                         int* __restrict__ seg) {
    int b = threadIdx.x;
    if (b > NB) return;
    int is32 = flag[0];
    int lo = 0, hi = NPTS;
    while (lo < hi) { int mid = (lo + hi) >> 1; if (bval(batch, mid, is32) < b) lo = mid + 1; else hi = mid; }
    seg[b] = lo;
}

// ---- front-end: identical arithmetic to R12/R13 ----
__global__ void __launch_bounds__(256) k_front(
    const float* __restrict__ x, const float* __restrict__ pos,
    const float* __restrict__ w1f, const float* __restrict__ b1f,
    const float* __restrict__ w2f, const float* __restrict__ b2f,
    const float* __restrict__ w1p, const float* __restrict__ b1p,
    const float* __restrict__ w2p, const float* __restrict__ b2p,
    float* __restrict__ comb)
{
    __shared__ float s_w1f[48 * 32];
    __shared__ float s_w1p[35 * 32];
    __shared__ float s_b1f[32], s_w2f[32], s_b1p[32], s_w2p[32];
    __shared__ float s_b2[2];
    int t = threadIdx.x;
    for (int idx = t; idx < 48 * 32; idx += 256) s_w1f[idx] = w1f[idx];
    for (int idx = t; idx < 35 * 32; idx += 256) s_w1p[idx] = w1p[idx];
    if (t < 32) { s_b1f[t] = b1f[t]; s_w2f[t] = w2f[t]; s_b1p[t] = b1p[t]; s_w2p[t] = w2p[t]; }
    if (t == 0) { s_b2[0] = b2f[0]; s_b2[1] = b2p[0]; }
    __syncthreads();

    int i = blockIdx.x * 256 + t;

    float xr[16];
    const float4* x4 = (const float4*)(x + (long)i * 16);
    #pragma unroll
    for (int d4 = 0; d4 < 4; ++d4) {
        float4 v = x4[d4];
        xr[4 * d4] = v.x; xr[4 * d4 + 1] = v.y; xr[4 * d4 + 2] = v.z; xr[4 * d4 + 3] = v.w;
    }
    float p0 = pos[i * 3], p1 = pos[i * 3 + 1], p2 = pos[i * 3 + 2];

    float enc[32];
    #pragma unroll
    for (int f = 0; f < 16; ++f) {
        float fbf = (float)((double)f * (9.0 / 63.0) + 1.0);
        float a = __fmul_rn(p0, fbf);
        enc[2 * f] = np_sincos_f32(a, 0);
        enc[2 * f + 1] = np_sincos_f32(a, 1);
    }

    float h[32], hr[32];
    #pragma unroll
    for (int j = 0; j < 32; ++j) h[j] = 0.0f;
    #pragma unroll
    for (int k = 0; k < 16; ++k) {
        float v = xr[k];
        #pragma unroll
        for (int j = 0; j < 32; ++j) h[j] = __builtin_fmaf(v, s_w1f[k * 32 + j], h[j]);
    }
    for (int e = 0; e < 32; ++e) {
        float v = enc[e];
        #pragma unroll
        for (int j = 0; j < 32; ++j) h[j] = __builtin_fmaf(v, s_w1f[(16 + e) * 32 + j], h[j]);
    }
    #pragma unroll
    for (int j = 0; j < 32; ++j) hr[j] = fmaxf(__fadd_rn(h[j], s_b1f[j]), 0.0f);
    float fw = __fadd_rn(np_gemv32(hr, s_w2f), s_b2[0]);

    #pragma unroll
    for (int j = 0; j < 32; ++j) h[j] = 0.0f;
    {
        #pragma unroll
        for (int j = 0; j < 32; ++j) h[j] = __builtin_fmaf(p0, s_w1p[0 * 32 + j], h[j]);
        #pragma unroll
        for (int j = 0; j < 32; ++j) h[j] = __builtin_fmaf(p1, s_w1p[1 * 32 + j], h[j]);
        #pragma unroll
        for (int j = 0; j < 32; ++j) h[j] = __builtin_fmaf(p2, s_w1p[2 * 32 + j], h[j]);
    }
    for (int e = 0; e < 32; ++e) {
        float v = enc[e];
        #pragma unroll
        for (int j = 0; j < 32; ++j) h[j] = __builtin_fmaf(v, s_w1p[(3 + e) * 32 + j], h[j]);
    }
    #pragma unroll
    for (int j = 0; j < 32; ++j) hr[j] = fmaxf(__fadd_rn(h[j], s_b1p[j]), 0.0f);
    float pw = __fadd_rn(np_gemv32(hr, s_w2p), s_b2[1]);

    float m = fmaxf(fw, pw);
    float e0 = np_exp_f32(__fsub_rn(fw, m));
    float e1 = np_exp_f32(__fsub_rn(pw, m));
    float s = __fadd_rn(e0, e1);
    float sw0 = __fdiv_rn(e0, s);   // scales feat
    float sw1 = __fdiv_rn(e1, s);   // scales pe

    float* out = comb + (long)i * CDP;
    out[0] = __fmul_rn(p0, sw1);
    out[1] = __fmul_rn(p1, sw1);
    out[2] = __fmul_rn(p2, sw1);
    #pragma unroll
    for (int e = 0; e < 32; ++e) out[3 + e] = __fmul_rn(enc[e], sw1);
    #pragma unroll
    for (int k = 0; k < 16; ++k) out[35 + k] = __fmul_rn(xr[k], sw0);
    #pragma unroll
    for (int e = 0; e < 32; ++e) out[51 + e] = __fmul_rn(enc[e], sw0);
    out[83] = 0.0f;   // pad kept zero (fmaf(0,0,acc)=acc in knn)
}

// ---- segment stats: identical accumulation order; 8-deep load prefetch ----
__global__ void __launch_bounds__(128) k_stats(
    const float* __restrict__ comb, const int* __restrict__ seg,
    float* __restrict__ meanb, float* __restrict__ denb)
{
    int b = blockIdx.x;
    int d = threadIdx.x;
    if (d >= CD) return;
    int start = seg[b], end = seg[b + 1];
    float sum = 0.0f, ss = 0.0f;
    int r = start;
    for (; r + 8 <= end; r += 8) {
        float v0 = comb[(long)(r + 0) * CDP + d];
        float v1 = comb[(long)(r + 1) * CDP + d];
        float v2 = comb[(long)(r + 2) * CDP + d];
        float v3 = comb[(long)(r + 3) * CDP + d];
        float v4 = comb[(long)(r + 4) * CDP + d];
        float v5 = comb[(long)(r + 5) * CDP + d];
        float v6 = comb[(long)(r + 6) * CDP + d];
        float v7 = comb[(long)(r + 7) * CDP + d];
        sum = __fadd_rn(sum, v0); ss = __fadd_rn(ss, __fmul_rn(v0, v0));
        sum = __fadd_rn(sum, v1); ss = __fadd_rn(ss, __fmul_rn(v1, v1));
        sum = __fadd_rn(sum, v2); ss = __fadd_rn(ss, __fmul_rn(v2, v2));
        sum = __fadd_rn(sum, v3); ss = __fadd_rn(ss, __fmul_rn(v3, v3));
        sum = __fadd_rn(sum, v4); ss = __fadd_rn(ss, __fmul_rn(v4, v4));
        sum = __fadd_rn(sum, v5); ss = __fadd_rn(ss, __fmul_rn(v5, v5));
        sum = __fadd_rn(sum, v6); ss = __fadd_rn(ss, __fmul_rn(v6, v6));
        sum = __fadd_rn(sum, v7); ss = __fadd_rn(ss, __fmul_rn(v7, v7));
    }
    for (; r < end; ++r) {
        float c = comb[(long)r * CDP + d];
        sum = __fadd_rn(sum, c);
        ss = __fadd_rn(ss, __fmul_rn(c, c));
    }
    float cnt = (float)(end - start);
    float mn = __fdiv_rn(sum, fmaxf(cnt, 1.0f));
    float num = __fsub_rn(ss, __fmul_rn(__fmul_rn(cnt, mn), mn));
    float var = __fdiv_rn(num, fmaxf(__fsub_rn(cnt, 1.0f), 1.0f));
    if (var < 0.0f) var = 0.0f;
    meanb[b * CD + d] = mn;
    denb[b * CD + d] = __fadd_rn(__fsqrt_rn(var), 1e-8f);
}

// ---- z in place (float4 I/O); sq via np pairwise 8-acc tree — arithmetic identical ----
__global__ void __launch_bounds__(256) k_z(
    float* __restrict__ comb, const int* __restrict__ batch, const int* __restrict__ flag,
    const float* __restrict__ meanb, const float* __restrict__ denb,
    float* __restrict__ sqb)
{
    int r = blockIdx.x * 256 + threadIdx.x;
    int b = bval(batch, r, flag[0]);
    const float* mb = meanb + b * CD;
    const float* db = denb + b * CD;
    float4* row4 = (float4*)(comb + (long)r * CDP);
    float rv[CDP];
    #pragma unroll
    for (int d4 = 0; d4 < 21; ++d4) {
        float4 v = row4[d4];
        rv[4 * d4] = v.x; rv[4 * d4 + 1] = v.y; rv[4 * d4 + 2] = v.z; rv[4 * d4 + 3] = v.w;
    }
    float p[CD];
    for (int d = 0; d < CD; ++d) {
        float zz = __fdiv_rn(__fsub_rn(rv[d], mb[d]), db[d]);
        rv[d] = zz;
        p[d] = __fmul_rn(zz, zz);
    }
    rv[83] = 0.0f;
    #pragma unroll
    for (int d4 = 0; d4 < 21; ++d4) {
        float4 v;
        v.x = rv[4 * d4]; v.y = rv[4 * d4 + 1]; v.z = rv[4 * d4 + 2]; v.w = rv[4 * d4 + 3];
        row4[d4] = v;
    }
    float r0 = p[0], r1 = p[1], r2 = p[2], r3 = p[3];
    float r4 = p[4], r5 = p[5], r6 = p[6], r7 = p[7];
    #pragma unroll
    for (int i = 8; i < 80; i += 8) {
        r0 = __fadd_rn(r0, p[i]);     r1 = __fadd_rn(r1, p[i + 1]);
        r2 = __fadd_rn(r2, p[i + 2]); r3 = __fadd_rn(r3, p[i + 3]);
        r4 = __fadd_rn(r4, p[i + 4]); r5 = __fadd_rn(r5, p[i + 5]);
        r6 = __fadd_rn(r6, p[i + 6]); r7 = __fadd_rn(r7, p[i + 7]);
    }
    float res = __fadd_rn(__fadd_rn(__fadd_rn(r0, r1), __fadd_rn(r2, r3)),
                          __fadd_rn(__fadd_rn(r4, r5), __fadd_rn(r6, r7)));
    res = __fadd_rn(res, p[80]);
    res = __fadd_rn(res, p[81]);
    res = __fadd_rn(res, p[82]);
    sqb[r] = res;
}

// ---- KNN: global-streaming slices, no hot-loop LDS/barriers.
//      16 queries x 8 slices per 128-block; each lane scans j = lo+s step 8.
//      Dot chain bit-identical (d-ascending single fmaf chain).
//      LDS used only for the final 8-list merge (stride-33, conflict-free). ----
__global__ void __launch_bounds__(128) k_knn(
    const float* __restrict__ z, const float* __restrict__ sqb,
    const int* __restrict__ batch, const int* __restrict__ flag,
    const int* __restrict__ seg, int* __restrict__ out)
{
    __shared__ float s_kd[128 * MST];
    __shared__ int   s_ki[128 * MST];

    int t = threadIdx.x;
    int q = t >> 3, s = t & 7;
    int i = blockIdx.x * QPB + q;
    int is32 = flag[0];
    int bi = bval(batch, i, is32);
    int lo = seg[bi], hi = seg[bi + 1];

    float zq[CDP];
    const float4* z4 = (const float4*)(z + (long)i * CDP);
    #pragma unroll
    for (int d4 = 0; d4 < 21; ++d4) {
        float4 v = z4[d4];
        zq[4 * d4] = v.x; zq[4 * d4 + 1] = v.y; zq[4 * d4 + 2] = v.z; zq[4 * d4 + 3] = v.w;
    }
    float sqi = sqb[i];

    float kd[KNN]; int ki[KNN];
    #pragma unroll
    for (int k = 0; k < KNN; ++k) { kd[k] = INFINITY; ki[k] = 0x7fffffff; }

    for (int j = lo + s; j < hi; j += NSL) {
        const float4* zj4 = (const float4*)(z + (long)j * CDP);
        float acc = 0.0f;
        #pragma unroll
        for (int d4 = 0; d4 < 21; ++d4) {
            float4 v = zj4[d4];
            acc = __builtin_fmaf(zq[4 * d4],     v.x, acc);
            acc = __builtin_fmaf(zq[4 * d4 + 1], v.y, acc);
            acc = __builtin_fmaf(zq[4 * d4 + 2], v.z, acc);
            acc = __builtin_fmaf(zq[4 * d4 + 3], v.w, acc);
        }
        float dist = __fsub_rn(__fadd_rn(sqi, sqb[j]), __fmul_rn(2.0f, acc));
        if (dist < kd[KNN - 1] || (dist == kd[KNN - 1] && j < ki[KNN - 1])) {
            kd[KNN - 1] = dist; ki[KNN - 1] = j;
            #pragma unroll
            for (int k = KNN - 2; k >= 0; --k) {
                bool sw = (kd[k + 1] < kd[k]) || (kd[k + 1] == kd[k] && ki[k + 1] < ki[k]);
                if (sw) {
                    float td = kd[k]; kd[k] = kd[k + 1]; kd[k + 1] = td;
                    int ti = ki[k]; ki[k] = ki[k + 1]; ki[k + 1] = ti;
                }
            }
        }
    }

    #pragma unroll
    for (int k = 0; k < KNN; ++k) { s_kd[t * MST + k] = kd[k]; s_ki[t * MST + k] = ki[k]; }
    __syncthreads();

    if (s == 0) {
        int p[NSL];
        #pragma unroll
        for (int l = 0; l < NSL; ++l) p[l] = 0;
        int* orow = out;
        int* ocol = out + (long)NPTS * KNN;
        for (int k = 0; k < KNN; ++k) {
            float bd = INFINITY; int bix = 0x7fffffff; int bl = 0;
            #pragma unroll
            for (int l = 0; l < NSL; ++l) {
                int pp = p[l];
                float d = (pp < KNN) ? s_kd[(t + l) * MST + pp] : INFINITY;
                int  ii = (pp < KNN) ? s_ki[(t + l) * MST + pp] : 0x7fffffff;
                if (d < bd || (d == bd && ii < bix)) { bd = d; bix = ii; bl = l; }
            }
            #pragma unroll
            for (int l = 0; l < NSL; ++l) if (bl == l) p[l]++;
            orow[(long)i * KNN + k] = i;
            ocol[(long)i * KNN + k] = bix;
        }
    }
}

extern "C" void kernel_launch(void* const* d_in, const int* in_sizes, int n_in,
                              void* d_out, int out_size, void* d_ws, size_t ws_size,
                              hipStream_t stream)
{
    const float* x   = (const float*)d_in[0];
    const float* pos = (const float*)d_in[1];
    const int* batch = (const int*)d_in[2];
    const float* w1f = (const float*)d_in[3];
    const float* b1f = (const float*)d_in[4];
    const float* w2f = (const float*)d_in[5];
    const float* b2f = (const float*)d_in[6];
    const float* w1p = (const float*)d_in[7];
    const float* b1p = (const float*)d_in[8];
    const float* w2p = (const float*)d_in[9];
    const float* b2p = (const float*)d_in[10];

    char* ws = (char*)d_ws;
    float* comb  = (float*)(ws);                // N*84*4 = 5,505,024 (combined, then z in place)
    float* sqb   = (float*)(ws + 5505024);      // N*4    = 65,536
    float* meanb = (float*)(ws + 5570560);      // 664*4  = 2,656
    float* denb  = (float*)(ws + 5573216);      // 664*4  = 2,656
    int*   seg   = (int*)  (ws + 5575936);      // 9 ints
    int*   flag  = (int*)  (ws + 5576000);      // 1 int
    int* out = (int*)d_out;

    hipLaunchKernelGGL(k_flag, dim3(1), dim3(64), 0, stream, batch, flag);
    hipLaunchKernelGGL(k_bounds, dim3(1), dim3(16), 0, stream, batch, flag, seg);
    hipLaunchKernelGGL(k_front, dim3(NPTS / 256), dim3(256), 0, stream,
                       x, pos, w1f, b1f, w2f, b2f, w1p, b1p, w2p, b2p, comb);
    hipLaunchKernelGGL(k_stats, dim3(NB), dim3(128), 0, stream, comb, seg, meanb, denb);
    hipLaunchKernelGGL(k_z, dim3(NPTS / 256), dim3(256), 0, stream, comb, batch, flag, meanb, denb, sqb);
    hipLaunchKernelGGL(k_knn, dim3(NPTS / QPB), dim3(128), 0, stream, comb, sqb, batch, flag, seg, out);
}